// Round 13
// baseline (917.612 us; speedup 1.0000x reference)
//
#include <hip/hip_runtime.h>

#define NROWS 8192
#define DDIM 512
#define ZROWS 16384
#define BM 256
#define BN 256
#define BK 64
#define KTILES (DDIM / BK)     // 8
#define NLR_BLOCKS 1024        // 32 x 32 (tm x lr-col-panel)
#define NSYM_BLOCKS 528        // upper triangle incl diag of 32
#define NBLOCKS (NLR_BLOCKS + NSYM_BLOCKS)   // 1552

typedef __attribute__((ext_vector_type(8))) short short8;
typedef __attribute__((ext_vector_type(4))) float f32x4;

__device__ __forceinline__ unsigned short f2bf(float f) {
  unsigned int u = __float_as_uint(f);
  u = (u + 0x7FFFu + ((u >> 16) & 1u)) >> 16;
  return (unsigned short)u;
}

// Kernel 1: per-row L2 normalize both inputs, write bf16 Z = [zl; zr],
// and compute the fp32 diagonal cosine sim dlr[i] = zl_i . zr_i.
__global__ __launch_bounds__(256) void nrm_kernel(const float* __restrict__ left,
                                                  const float* __restrict__ right,
                                                  unsigned short* __restrict__ Z,
                                                  float* __restrict__ dlr) {
  const int i = blockIdx.x;
  const int t = threadIdx.x;
  const float2 lv = ((const float2*)(left + (size_t)i * DDIM))[t];
  const float2 rv = ((const float2*)(right + (size_t)i * DDIM))[t];
  float ssl = lv.x * lv.x + lv.y * lv.y;
  float ssr = rv.x * rv.x + rv.y * rv.y;
  float slr = lv.x * rv.x + lv.y * rv.y;
#pragma unroll
  for (int m = 1; m < 64; m <<= 1) {
    ssl += __shfl_xor(ssl, m);
    ssr += __shfl_xor(ssr, m);
    slr += __shfl_xor(slr, m);
  }
  __shared__ float red[3][4];
  const int w = t >> 6;
  if ((t & 63) == 0) { red[0][w] = ssl; red[1][w] = ssr; red[2][w] = slr; }
  __syncthreads();
  ssl = red[0][0] + red[0][1] + red[0][2] + red[0][3];
  ssr = red[1][0] + red[1][1] + red[1][2] + red[1][3];
  slr = red[2][0] + red[2][1] + red[2][2] + red[2][3];
  const float invl = 1.0f / fmaxf(sqrtf(ssl), 1e-12f);
  const float invr = 1.0f / fmaxf(sqrtf(ssr), 1e-12f);
  if (t == 0) dlr[i] = slr * invl * invr;
  ushort2 zl2; zl2.x = f2bf(lv.x * invl); zl2.y = f2bf(lv.y * invl);
  ushort2 zr2; zr2.x = f2bf(rv.x * invr); zr2.y = f2bf(rv.y * invr);
  ((ushort2*)(Z + (size_t)i * DDIM))[t] = zl2;
  ((ushort2*)(Z + (size_t)(NROWS + i) * DDIM))[t] = zr2;
}

// Kernel 2: fused GEMM + exp-rowsum with ll-symmetry.
// SINGLE-buffered 256x256, LDS = exactly 64 KiB -> TWO blocks/CU target.
// Evidence: R2 (2 co-resident blocks) ran 256 MFMA-insts/CU in 3844 cyc vs
// 7274 for every 1-block 256^2 schedule (R5-R12) — co-resident blocks
// de-phase and fill each other's VM0/barrier drains (m97/m114 mechanism).
// __launch_bounds__(512,4): 4 waves/EU -> k = 2 blocks/CU; caps VGPR at 128
// (= current usage; acc lives in AGPRs).
// Per kt (m97-plain): STAGE(kt); VM0; BAR; reads+MFMA; BAR.
// Overwrite-safety: reads of kt precede MFMA precede BAR(kt); STAGE(kt+1)
// comes after BAR(kt). Visibility: VM0 before BAR makes DMA-landed
// collective. Epilogue overlays reductions onto sB (all reads done at the
// final in-loop BAR; all DMA drained by kt7's VM0).
__global__ __launch_bounds__(512, 4) void sim_kernel(const unsigned short* __restrict__ Z,
                                                     float* __restrict__ partial) {
  __shared__ __align__(16) unsigned short sA[BM * BK];   // 32 KiB
  __shared__ __align__(16) unsigned short sB[BN * BK];   // 32 KiB  (total 64 KiB)

  // ---- block decode
  int tm, tn; bool sym = false;
  {
    const int bid = blockIdx.x;
    if (bid < NLR_BLOCKS) {
      tm = bid >> 5; tn = 32 + (bid & 31);
    } else {
      const int b2 = bid - NLR_BLOCKS;            // 0..527
      int i = (int)(32.5f - sqrtf(32.5f * 32.5f - 2.0f * (float)b2));
      if (i < 0) i = 0; if (i > 31) i = 31;
      while (i > 0 && (32 * i - i * (i - 1) / 2) > b2) --i;
      while (i < 31 && (32 * (i + 1) - (i + 1) * i / 2) <= b2) ++i;
      tm = i; tn = i + (b2 - (32 * i - i * (i - 1) / 2));
      sym = (tn != tm);
    }
  }

  const int t = threadIdx.x;
  const int l = t & 63;
  const int w = t >> 6;        // wave 0..7
  const int wm = w >> 2;       // 0..1  (128-row slab)
  const int wn = w & 3;        // 0..3  (64-col slab)
  const int lr = l & 15;
  const int lk = l >> 4;       // 0..3

  f32x4 acc[8][4];
#pragma unroll
  for (int a = 0; a < 8; ++a)
#pragma unroll
    for (int b = 0; b < 4; ++b)
#pragma unroll
      for (int r = 0; r < 4; ++r) acc[a][b][r] = 0.0f;

  const unsigned short* Abase = Z + (size_t)tm * BM * DDIM;
  const unsigned short* Bbase = Z + (size_t)tn * BN * DDIM;

  // Staging: element e = j*512 + t; LDS slot-linear; global source slot
  // pre-swizzled by row&7; matching XOR on ds_read (verified conflict-free).
  const int srow = t >> 3;                       // 0..63
  const int scol = ((t & 7) ^ (srow & 7)) * 8;   // swizzled source element col

#define STAGE_AJ(k0, j)                                                           \
  __builtin_amdgcn_global_load_lds(                                               \
      (const __attribute__((address_space(1))) void*)(Abase +                     \
          (size_t)((j) * 64 + srow) * DDIM + (k0) + scol),                        \
      (__attribute__((address_space(3))) void*)(&sA[((j) * 512 + t) * 8]),        \
      16, 0, 0);
#define STAGE_BJ(k0, j)                                                           \
  __builtin_amdgcn_global_load_lds(                                               \
      (const __attribute__((address_space(1))) void*)(Bbase +                     \
          (size_t)((j) * 64 + srow) * DDIM + (k0) + scol),                        \
      (__attribute__((address_space(3))) void*)(&sB[((j) * 512 + t) * 8]),        \
      16, 0, 0);
#define STAGE_ALL(k0) { STAGE_AJ(k0, 0) STAGE_AJ(k0, 1)                           \
                        STAGE_AJ(k0, 2) STAGE_AJ(k0, 3)                           \
                        STAGE_BJ(k0, 0) STAGE_BJ(k0, 1)                           \
                        STAGE_BJ(k0, 2) STAGE_BJ(k0, 3) }

  short8 af[4][2], ag[4][2], bf[4][2];

#define DS_A(dst, fmb)                                                             \
  _Pragma("unroll")                                                                \
  for (int fm = 0; fm < 4; ++fm)                                                   \
    _Pragma("unroll")                                                              \
    for (int ks = 0; ks < 2; ++ks) {                                               \
      const int row = wm * 128 + ((fmb) + fm) * 16 + lr;                           \
      dst[fm][ks] = *(const short8*)&sA[row * BK + ((ks * 4 + lk) ^ (lr & 7)) * 8]; \
    }

#define DS_B2(fnb)                                                                 \
  _Pragma("unroll")                                                                \
  for (int fn = 0; fn < 2; ++fn)                                                   \
    _Pragma("unroll")                                                              \
    for (int ks = 0; ks < 2; ++ks) {                                               \
      const int row = wn * 64 + ((fnb) + fn) * 16 + lr;                            \
      bf[(fnb) + fn][ks] = *(const short8*)&sB[row * BK + ((ks * 4 + lk) ^ (lr & 7)) * 8]; \
    }

// ks OUTER: consecutive MFMAs hit distinct accumulators (dep distance 8).
#define MFMA16(A, fmb, fnb)                                                        \
  __builtin_amdgcn_s_setprio(1);                                                   \
  _Pragma("unroll")                                                                \
  for (int ks = 0; ks < 2; ++ks)                                                   \
    _Pragma("unroll")                                                              \
    for (int fm = 0; fm < 4; ++fm)                                                 \
      _Pragma("unroll")                                                            \
      for (int fn = 0; fn < 2; ++fn)                                               \
        acc[(fmb) + fm][(fnb) + fn] =                                              \
            __builtin_amdgcn_mfma_f32_16x16x32_bf16(A[fm][ks], bf[(fnb) + fn][ks], \
                                                    acc[(fmb) + fm][(fnb) + fn],   \
                                                    0, 0, 0);                      \
  __builtin_amdgcn_s_setprio(0);

#define BARF  { __builtin_amdgcn_s_barrier(); asm volatile("" ::: "memory"); }
#define VM0   asm volatile("s_waitcnt vmcnt(0)" ::: "memory")

#pragma unroll 1
  for (int kt = 0; kt < KTILES; ++kt) {
    // stage kt into the single buffer (all readers of kt-1 passed BAR(kt-1))
    STAGE_ALL(kt * BK);
    VM0;                       // exposed drain — the co-resident block covers it
    BARF;
    // reads + MFMA, cluster-interleaved; compiler pipelines with fine lgkmcnt
    DS_A(af, 0); DS_B2(0);
    MFMA16(af, 0, 0);
    DS_B2(2);
    MFMA16(af, 0, 2);
    DS_A(ag, 4);
    MFMA16(ag, 4, 0);
    MFMA16(ag, 4, 2);
    BARF;                      // all reads of kt done -> licenses STAGE(kt+1)
  }

  // ---- Epilogue: e = exp(2*s); rowsums always, colsums when sym.
  // C/D layout (16x16x32): col = lane&15, row = (lane>>4)*4 + reg.
  // Overlay reductions onto sB (dead: all reads done at final in-loop BAR,
  // all DMA drained by kt7's VM0).
  float* rsum = (float*)&sB[0];           // 256 floats
  float* csum = rsum + BM;                // 256 floats
  if (t < BM) { rsum[t] = 0.0f; csum[t] = 0.0f; }
  __syncthreads();
  float c0 = 0.0f, c1 = 0.0f, c2 = 0.0f, c3 = 0.0f;
#pragma unroll
  for (int fm = 0; fm < 8; ++fm) {
#pragma unroll
    for (int r = 0; r < 4; ++r) {
      float e0 = __expf(2.0f * acc[fm][0][r]);
      float e1 = __expf(2.0f * acc[fm][1][r]);
      float e2 = __expf(2.0f * acc[fm][2][r]);
      float e3 = __expf(2.0f * acc[fm][3][r]);
      float v = e0 + e1 + e2 + e3;
      v += __shfl_xor(v, 1);
      v += __shfl_xor(v, 2);
      v += __shfl_xor(v, 4);
      v += __shfl_xor(v, 8);
      if (lr == 0) atomicAdd(&rsum[wm * 128 + fm * 16 + lk * 4 + r], v);
      c0 += e0; c1 += e1; c2 += e2; c3 += e3;
    }
  }
  if (sym) {
    c0 += __shfl_xor(c0, 16); c0 += __shfl_xor(c0, 32);
    c1 += __shfl_xor(c1, 16); c1 += __shfl_xor(c1, 32);
    c2 += __shfl_xor(c2, 16); c2 += __shfl_xor(c2, 32);
    c3 += __shfl_xor(c3, 16); c3 += __shfl_xor(c3, 32);
    if (l < 16) {   // one lane per column per wave; 2 waves (wm) share a col
      atomicAdd(&csum[wn * 64 +  0 + lr], c0);
      atomicAdd(&csum[wn * 64 + 16 + lr], c1);
      atomicAdd(&csum[wn * 64 + 32 + lr], c2);
      atomicAdd(&csum[wn * 64 + 48 + lr], c3);
    }
  }
  __syncthreads();
  if (t < BM) partial[(size_t)tn * NROWS + tm * BM + t] = rsum[t];
  if (sym && t < BM) partial[(size_t)tm * NROWS + tn * BM + t] = csum[t];
}

// Kernel 3: reduce partials, final loss.
// loss[i] = log(rowsum - e^2) - 2*dlr[i]
__global__ __launch_bounds__(256) void fin_kernel(const float* __restrict__ partial,
                                                  const float* __restrict__ dlr,
                                                  float* __restrict__ out) {
  const int i = blockIdx.x * 256 + threadIdx.x;
  float s = 0.0f;
#pragma unroll 8
  for (int p = 0; p < 64; ++p) s += partial[(size_t)p * NROWS + i];
  out[i] = logf(s - 7.38905609893065f) - 2.0f * dlr[i];
}

extern "C" void kernel_launch(void* const* d_in, const int* in_sizes, int n_in,
                              void* d_out, int out_size, void* d_ws, size_t ws_size,
                              hipStream_t stream) {
  const float* left = (const float*)d_in[0];
  const float* right = (const float*)d_in[1];
  float* out = (float*)d_out;

  unsigned short* Z = (unsigned short*)d_ws;                       // 16 MB
  char* p = (char*)d_ws + (size_t)ZROWS * DDIM * 2;
  float* dlr = (float*)p;                                          // 32 KB
  float* partial = (float*)(p + (size_t)NROWS * 4);                // 2 MB

  nrm_kernel<<<NROWS, 256, 0, stream>>>(left, right, Z, dlr);
  sim_kernel<<<NBLOCKS, 512, 0, stream>>>(Z, partial);
  fin_kernel<<<NROWS / 256, 256, 0, stream>>>(partial, dlr, out);
}

// Round 14
// 134.971 us; speedup vs baseline: 6.7986x; 6.7986x over previous
//
#include <hip/hip_runtime.h>

#define NROWS 8192
#define DDIM 512
#define ZROWS 16384
#define BM 128
#define BN 128
#define BK 64
#define KTILES (DDIM / BK)     // 8
#define NLR_BLOCKS 4096        // 64 x 64 (tm x lr-col-panel)
#define NSYM_BLOCKS 2080       // upper triangle incl diag of 64
#define NBLOCKS (NLR_BLOCKS + NSYM_BLOCKS)   // 6176
#define NPANELS 128            // 16384 / 128 col panels

typedef __attribute__((ext_vector_type(8))) short short8;
typedef __attribute__((ext_vector_type(4))) float f32x4;

__device__ __forceinline__ unsigned short f2bf(float f) {
  unsigned int u = __float_as_uint(f);
  u = (u + 0x7FFFu + ((u >> 16) & 1u)) >> 16;
  return (unsigned short)u;
}

// Kernel 1: per-row L2 normalize both inputs, write bf16 Z = [zl; zr],
// and compute the fp32 diagonal cosine sim dlr[i] = zl_i . zr_i.
__global__ __launch_bounds__(256) void nrm_kernel(const float* __restrict__ left,
                                                  const float* __restrict__ right,
                                                  unsigned short* __restrict__ Z,
                                                  float* __restrict__ dlr) {
  const int i = blockIdx.x;
  const int t = threadIdx.x;
  const float2 lv = ((const float2*)(left + (size_t)i * DDIM))[t];
  const float2 rv = ((const float2*)(right + (size_t)i * DDIM))[t];
  float ssl = lv.x * lv.x + lv.y * lv.y;
  float ssr = rv.x * rv.x + rv.y * rv.y;
  float slr = lv.x * rv.x + lv.y * rv.y;
#pragma unroll
  for (int m = 1; m < 64; m <<= 1) {
    ssl += __shfl_xor(ssl, m);
    ssr += __shfl_xor(ssr, m);
    slr += __shfl_xor(slr, m);
  }
  __shared__ float red[3][4];
  const int w = t >> 6;
  if ((t & 63) == 0) { red[0][w] = ssl; red[1][w] = ssr; red[2][w] = slr; }
  __syncthreads();
  ssl = red[0][0] + red[0][1] + red[0][2] + red[0][3];
  ssr = red[1][0] + red[1][1] + red[1][2] + red[1][3];
  slr = red[2][0] + red[2][1] + red[2][2] + red[2][3];
  const float invl = 1.0f / fmaxf(sqrtf(ssl), 1e-12f);
  const float invr = 1.0f / fmaxf(sqrtf(ssr), 1e-12f);
  if (t == 0) dlr[i] = slr * invl * invr;
  ushort2 zl2; zl2.x = f2bf(lv.x * invl); zl2.y = f2bf(lv.y * invl);
  ushort2 zr2; zr2.x = f2bf(rv.x * invr); zr2.y = f2bf(rv.y * invr);
  ((ushort2*)(Z + (size_t)i * DDIM))[t] = zl2;
  ((ushort2*)(Z + (size_t)(NROWS + i) * DDIM))[t] = zr2;
}

// Kernel 2: fused GEMM + exp-rowsum with ll-symmetry at 128^2 granularity.
// 128x128 tile, 4 waves (2x2, wave tile 64x64), SINGLE-buffered 32 KiB LDS,
// __launch_bounds__(256,4) -> 4 blocks/CU (16 waves/CU), regs/wave ~116
// (acc 64 + frags 32 + addr) <= 128 cap. R13 proved launch_bounds forces
// co-residency; 256^2 spilled (needs ~240 regs); 128^2 fits. Co-resident
// blocks de-phase and cover each other's VM0/barrier drains (m97/m114; R2's
// 2-block 128^2 was the best cycle-efficiency of all 12 rounds).
// Per kt: STAGE(8 gloads); VM0; BAR; 16 ds_read + 32 MFMA (ks-outer,
// setprio); BAR. Zero-conflict swizzle (verified). Spill signature to watch:
// FETCH_SIZE >> 500 MB.
__global__ __launch_bounds__(256, 4) void sim_kernel(const unsigned short* __restrict__ Z,
                                                     float* __restrict__ partial) {
  __shared__ __align__(16) unsigned short sA[BM * BK];   // 16 KiB
  __shared__ __align__(16) unsigned short sB[BN * BK];   // 16 KiB (total 32 KiB)

  // ---- block decode (lr: 64x64; ll: upper triangle of 64)
  int tm, tn; bool sym = false;
  {
    const int bid = blockIdx.x;
    if (bid < NLR_BLOCKS) {
      tm = bid >> 6; tn = 64 + (bid & 63);
    } else {
      const int b2 = bid - NLR_BLOCKS;            // 0..2079
      int i = (int)(64.5f - sqrtf(64.5f * 64.5f - 2.0f * (float)b2));
      if (i < 0) i = 0; if (i > 63) i = 63;
      while (i > 0 && (64 * i - i * (i - 1) / 2) > b2) --i;
      while (i < 63 && (64 * (i + 1) - (i + 1) * i / 2) <= b2) ++i;
      tm = i; tn = i + (b2 - (64 * i - i * (i - 1) / 2));
      sym = (tn != tm);
    }
  }

  const int t = threadIdx.x;
  const int l = t & 63;
  const int w = t >> 6;        // wave 0..3
  const int wm = w >> 1;       // 0..1  (64-row slab)
  const int wn = w & 1;        // 0..1  (64-col slab)
  const int lr = l & 15;
  const int lk = l >> 4;       // 0..3

  f32x4 acc[4][4];
#pragma unroll
  for (int a = 0; a < 4; ++a)
#pragma unroll
    for (int b = 0; b < 4; ++b)
#pragma unroll
      for (int r = 0; r < 4; ++r) acc[a][b][r] = 0.0f;

  const unsigned short* Abase = Z + (size_t)tm * BM * DDIM;
  const unsigned short* Bbase = Z + (size_t)tn * BN * DDIM;

  // Staging: 256 threads x 16 B = 4 KB = 32 rows (128 B each) per gload.
  // LDS slot-linear; global source slot pre-swizzled by row&7; matching XOR
  // on ds_read (verified conflict-free).
  const int srow = t >> 3;                       // 0..31
  const int scol = ((t & 7) ^ (srow & 7)) * 8;   // swizzled source element col

#define STAGE_AJ(k0, j)                                                           \
  __builtin_amdgcn_global_load_lds(                                               \
      (const __attribute__((address_space(1))) void*)(Abase +                     \
          (size_t)((j) * 32 + srow) * DDIM + (k0) + scol),                        \
      (__attribute__((address_space(3))) void*)(&sA[((j) * 256 + t) * 8]),        \
      16, 0, 0);
#define STAGE_BJ(k0, j)                                                           \
  __builtin_amdgcn_global_load_lds(                                               \
      (const __attribute__((address_space(1))) void*)(Bbase +                     \
          (size_t)((j) * 32 + srow) * DDIM + (k0) + scol),                        \
      (__attribute__((address_space(3))) void*)(&sB[((j) * 256 + t) * 8]),        \
      16, 0, 0);
#define STAGE_ALL(k0) { STAGE_AJ(k0, 0) STAGE_AJ(k0, 1)                           \
                        STAGE_AJ(k0, 2) STAGE_AJ(k0, 3)                           \
                        STAGE_BJ(k0, 0) STAGE_BJ(k0, 1)                           \
                        STAGE_BJ(k0, 2) STAGE_BJ(k0, 3) }

  short8 af[4][2], bf[4][2];

#define DS_A(fmb)                                                                  \
  _Pragma("unroll")                                                                \
  for (int fm = 0; fm < 4; ++fm)                                                   \
    _Pragma("unroll")                                                              \
    for (int ks = 0; ks < 2; ++ks) {                                               \
      const int row = wm * 64 + fm * 16 + lr;                                      \
      af[fm][ks] = *(const short8*)&sA[row * BK + ((ks * 4 + lk) ^ (lr & 7)) * 8]; \
    }

#define DS_B2(fnb)                                                                 \
  _Pragma("unroll")                                                                \
  for (int fn = 0; fn < 2; ++fn)                                                   \
    _Pragma("unroll")                                                              \
    for (int ks = 0; ks < 2; ++ks) {                                               \
      const int row = wn * 64 + ((fnb) + fn) * 16 + lr;                            \
      bf[(fnb) + fn][ks] = *(const short8*)&sB[row * BK + ((ks * 4 + lk) ^ (lr & 7)) * 8]; \
    }

// ks OUTER: consecutive MFMAs hit distinct accumulators (dep distance 8).
#define MFMA16(fnb)                                                                \
  __builtin_amdgcn_s_setprio(1);                                                   \
  _Pragma("unroll")                                                                \
  for (int ks = 0; ks < 2; ++ks)                                                   \
    _Pragma("unroll")                                                              \
    for (int fm = 0; fm < 4; ++fm)                                                 \
      _Pragma("unroll")                                                            \
      for (int fn = 0; fn < 2; ++fn)                                               \
        acc[fm][(fnb) + fn] =                                                      \
            __builtin_amdgcn_mfma_f32_16x16x32_bf16(af[fm][ks], bf[(fnb) + fn][ks],\
                                                    acc[fm][(fnb) + fn],           \
                                                    0, 0, 0);                      \
  __builtin_amdgcn_s_setprio(0);

#define BARF  { __builtin_amdgcn_s_barrier(); asm volatile("" ::: "memory"); }
#define VM0   asm volatile("s_waitcnt vmcnt(0)" ::: "memory")

#pragma unroll 1
  for (int kt = 0; kt < KTILES; ++kt) {
    STAGE_ALL(kt * BK);
    VM0;                       // exposed drain — covered by 3 co-resident blocks
    BARF;
    DS_A(0); DS_B2(0);
    MFMA16(0);
    DS_B2(2);
    MFMA16(2);
    BARF;                      // all reads of kt done -> licenses STAGE(kt+1)
  }

  // ---- Epilogue: e = exp(2*s); rowsums always, colsums when sym.
  // C/D layout (16x16x32): col = lane&15, row = (lane>>4)*4 + reg.
  // Overlay reductions onto sB (dead after final BAR; DMA drained at kt7 VM0).
  float* rsum = (float*)&sB[0];           // 128 floats
  float* csum = rsum + BM;                // 128 floats
  if (t < BM) { rsum[t] = 0.0f; csum[t] = 0.0f; }
  __syncthreads();
  float c0 = 0.0f, c1 = 0.0f, c2 = 0.0f, c3 = 0.0f;
#pragma unroll
  for (int fm = 0; fm < 4; ++fm) {
#pragma unroll
    for (int r = 0; r < 4; ++r) {
      float e0 = __expf(2.0f * acc[fm][0][r]);
      float e1 = __expf(2.0f * acc[fm][1][r]);
      float e2 = __expf(2.0f * acc[fm][2][r]);
      float e3 = __expf(2.0f * acc[fm][3][r]);
      float v = e0 + e1 + e2 + e3;
      v += __shfl_xor(v, 1);
      v += __shfl_xor(v, 2);
      v += __shfl_xor(v, 4);
      v += __shfl_xor(v, 8);
      if (lr == 0) atomicAdd(&rsum[wm * 64 + fm * 16 + lk * 4 + r], v);
      c0 += e0; c1 += e1; c2 += e2; c3 += e3;
    }
  }
  if (sym) {
    c0 += __shfl_xor(c0, 16); c0 += __shfl_xor(c0, 32);
    c1 += __shfl_xor(c1, 16); c1 += __shfl_xor(c1, 32);
    c2 += __shfl_xor(c2, 16); c2 += __shfl_xor(c2, 32);
    c3 += __shfl_xor(c3, 16); c3 += __shfl_xor(c3, 32);
    if (l < 16) {   // one lane per column per wave; 2 waves (wm) share a col
      atomicAdd(&csum[wn * 64 +  0 + lr], c0);
      atomicAdd(&csum[wn * 64 + 16 + lr], c1);
      atomicAdd(&csum[wn * 64 + 32 + lr], c2);
      atomicAdd(&csum[wn * 64 + 48 + lr], c3);
    }
  }
  __syncthreads();
  if (t < BM) partial[(size_t)tn * NROWS + tm * BM + t] = rsum[t];
  if (sym && t < BM) partial[(size_t)tm * NROWS + tn * BM + t] = csum[t];
}

// Kernel 3: reduce partials, final loss.
// loss[i] = log(rowsum - e^2) - 2*dlr[i]
__global__ __launch_bounds__(256) void fin_kernel(const float* __restrict__ partial,
                                                  const float* __restrict__ dlr,
                                                  float* __restrict__ out) {
  const int i = blockIdx.x * 256 + threadIdx.x;
  float s = 0.0f;
#pragma unroll 8
  for (int p = 0; p < NPANELS; ++p) s += partial[(size_t)p * NROWS + i];
  out[i] = logf(s - 7.38905609893065f) - 2.0f * dlr[i];
}

extern "C" void kernel_launch(void* const* d_in, const int* in_sizes, int n_in,
                              void* d_out, int out_size, void* d_ws, size_t ws_size,
                              hipStream_t stream) {
  const float* left = (const float*)d_in[0];
  const float* right = (const float*)d_in[1];
  float* out = (float*)d_out;

  unsigned short* Z = (unsigned short*)d_ws;                       // 16 MB
  char* p = (char*)d_ws + (size_t)ZROWS * DDIM * 2;
  float* dlr = (float*)p;                                          // 32 KB
  float* partial = (float*)(p + (size_t)NROWS * 4);                // 4 MB

  nrm_kernel<<<NROWS, 256, 0, stream>>>(left, right, Z, dlr);
  sim_kernel<<<NBLOCKS, 256, 0, stream>>>(Z, partial);
  fin_kernel<<<NROWS / 256, 256, 0, stream>>>(partial, dlr, out);
}